// Round 5
// baseline (156.616 us; speedup 1.0000x reference)
//
#include <hip/hip_runtime.h>

#define NT 10          // trees
#define NL 16          // leaves per tree
#define NN 31          // nodes per tree
#define DD 256         // hidden dim
#define G4 1024        // 4*D gates
#define NNODES (NT*NN) // 310
#define NPATH (NT*NL)  // 160
#define NB 4096

// ---------------------------------------------------------------------------
// Generation-safe flag protocol (zero-init at module load; monotone; survive
// ws poison since they live in __device__ space).
//  g_xgf[nt]     : +16/launch (16 mt-blocks of column-group nt, RELEASE)
//  g_tf[s][t][dt]: +1/launch by tree block (t,dt) after step s+1 (RELEASE)
//  g_h4f[t]      : +16/launch (16 dt-blocks of tree t, RELEASE)
//  g_sgen[sb]    : +1/launch by scatter block sb (private generation word)
// Generation G for a waiter is read from a word ONLY ITSELF bumps (tree:
// g_tf[0][t][dt]; scatter: g_sgen[sb]) BEFORE its own bump -> stable under
// any dispatch order and graph replay. Targets compared wrap-safe.
//
// Ordering (the R4 lesson): relaxed bump-after-barrier is NOT enough — the
// flag RMW goes straight to the coherence point while write-through data may
// still be in the local XCD L2. Producer bumps are RELEASE (vmcnt drain +
// L2 writeback precede the RMW); consumers fence ACQUIRE (L1/L2 invalidate)
// between poll-success and data loads.
// ---------------------------------------------------------------------------
__device__ unsigned g_xgf[16];
__device__ unsigned g_tf[3][NT][16];
__device__ unsigned g_h4f[NT];
__device__ unsigned g_sgen[256];

__device__ __forceinline__ float sigf(float x)   { return 1.0f / (1.0f + __expf(-x)); }
__device__ __forceinline__ float tanh_f(float x) { return 2.0f / (1.0f + __expf(-2.0f*x)) - 1.0f; }

__device__ __forceinline__ void co_store(float* p, float v) {
    union { float f; unsigned u; } c; c.f = v;
    __hip_atomic_store((unsigned*)p, c.u, __ATOMIC_RELAXED, __HIP_MEMORY_SCOPE_AGENT);
}
__device__ __forceinline__ float co_load(const float* p) {
    union { unsigned u; float f; } c;
    c.u = __hip_atomic_load((const unsigned*)p, __ATOMIC_RELAXED, __HIP_MEMORY_SCOPE_AGENT);
    return c.f;
}
__device__ __forceinline__ unsigned long long co_load64(const unsigned long long* p) {
    return __hip_atomic_load(p, __ATOMIC_RELAXED, __HIP_MEMORY_SCOPE_AGENT);
}
__device__ __forceinline__ unsigned flag_load(const unsigned* p) {
    return __hip_atomic_load(p, __ATOMIC_RELAXED, __HIP_MEMORY_SCOPE_AGENT);
}
__device__ __forceinline__ void rel_add(unsigned* p) {
    __hip_atomic_fetch_add(p, 1u, __ATOMIC_RELEASE, __HIP_MEMORY_SCOPE_AGENT);
}
__device__ __forceinline__ void acq_fence() {
    __builtin_amdgcn_fence(__ATOMIC_ACQUIRE, "agent");
}

// ---------------------------------------------------------------------------
// ONE kernel, 672 blocks x 256 threads:
//   blocks   0..159 : tree-steps  (t = bid>>4, dt = bid&15)
//   blocks 160..415 : nodeproj    (mt = (bid-160)>>4, nt = (bid-160)&15)
//   blocks 416..671 : scatter     (sb = bid-416, 160 output rows each)
// Deadlock-free: __launch_bounds__(256,3) + 41.3KB LDS gives >=3 blocks/CU
// -> 768 >= 672 co-resident under any dispatch order.
// ---------------------------------------------------------------------------
__global__ __launch_bounds__(256, 3) void k_fused(
    const float* __restrict__ cross, const float* __restrict__ emb,
    const float* __restrict__ Wih,   const float* __restrict__ Whh,
    const float* __restrict__ bih,   const float* __restrict__ bhh,
    float* __restrict__ xg,
    float* __restrict__ h1g, float* __restrict__ h2g,
    float* __restrict__ h3g, float* __restrict__ h4g,
    float* __restrict__ out)
{
    __shared__ float smem[10320];          // union across the three roles
    const int tid = threadIdx.x;
    const int bid = blockIdx.x;

    if (bid < 160) {
        // ================= TREE-STEPS =================
        float* hs   = smem;                // 8*256 input h rows
        float* ps   = smem + 2048;         // 8*256 GEMM partials
        float* cbuf = smem + 4096;         // 2 x 8*16 c ping-pong
        float4* hs4 = (float4*)hs;

        const int t    = bid >> 4;
        const int dt   = bid & 15;
        const int kq   = tid >> 6;
        const int w    = tid & 63;
        const int gate = w >> 4;
        const int col  = w & 15;

        // generation from a word only THIS block bumps (read precedes bump)
        unsigned G = 0;
        if (tid < 64) G = flag_load(&g_tf[0][t][dt]);

        // W_hh quarter-rows -> registers (overlaps the nodeproj wait)
        const float4* W4 = (const float4*)Whh
            + (size_t)(gate * DD + dt * 16 + col) * 64 + kq * 16;
        float4 wreg[16];
        #pragma unroll
        for (int j = 0; j < 16; ++j) wreg[j] = W4[j];

        // wait for all 256 nodeproj blocks (16 per nt-word)
        if (tid < 64) {
            const unsigned tgt = 16u * (G + 1u);
            for (;;) {
                bool ok = true;
                if (tid < 16)
                    ok = (int)(flag_load(&g_xgf[tid]) - tgt) >= 0;
                if (__all(ok)) break;
                __builtin_amdgcn_s_sleep(2);
            }
        }
        __syncthreads();
        acq_fence();                       // xg now safe to read

        // xn gate biases for steps 1..4
        float xnv[4][4];
        #pragma unroll
        for (int s = 1; s <= 4; ++s) {
            xnv[s-1][0] = xnv[s-1][1] = xnv[s-1][2] = xnv[s-1][3] = 0.f;
            if (tid < (32 << (s - 1))) {
                int node = (1 << s) - 1 + (tid >> 4);
                const float* xn = xg + (size_t)(t * NN + node) * G4
                                     + dt * 16 + (tid & 15);
                xnv[s-1][0] = co_load(xn);
                xnv[s-1][1] = co_load(xn + 256);
                xnv[s-1][2] = co_load(xn + 512);
                xnv[s-1][3] = co_load(xn + 768);
            }
        }

        // root step: elementwise, full width (h(-1)=c(-1)=0)
        {
            const float* xr = xg + (size_t)(t * NN) * G4;
            float r_i = co_load(xr + tid);
            float r_g = co_load(xr + 512 + tid);
            float r_o = co_load(xr + 768 + tid);
            float c0 = sigf(r_i) * tanh_f(r_g);
            hs[tid]  = sigf(r_o) * tanh_f(c0);
            if ((tid >> 4) == dt) cbuf[tid & 15] = c0;
        }
        __syncthreads();

        float* hout[3] = { h1g, h2g, h3g };
        const float* hin[3] = { h1g, h2g, h3g };

        #pragma unroll
        for (int s = 1; s <= 4; ++s) {
            const int L = 1 << (s - 1);

            if (s > 1) {
                if (tid < 64) {
                    const unsigned tgt = G + 1u;
                    for (;;) {
                        bool ok = true;
                        if (tid < 16)
                            ok = (int)(flag_load(&g_tf[s - 2][t][tid]) - tgt) >= 0;
                        if (__all(ok)) break;
                        __builtin_amdgcn_s_sleep(1);
                    }
                }
                __syncthreads();
                acq_fence();               // h rows now safe to read
                const unsigned long long* src =
                    (const unsigned long long*)(hin[s - 2] + (size_t)t * L * DD);
                unsigned long long raw[4];
                #pragma unroll
                for (int r = 0; r < L / 2; ++r)
                    raw[r] = co_load64(src + tid + 256 * r);
                float2* hs2 = (float2*)hs;
                #pragma unroll
                for (int r = 0; r < L / 2; ++r) {
                    union { unsigned long long u; float2 f; } cv; cv.u = raw[r];
                    hs2[tid + 256 * r] = cv.f;
                }
                __syncthreads();
            }

            float acc[8];
            #pragma unroll
            for (int p = 0; p < 8; ++p) acc[p] = 0.f;
            #pragma unroll
            for (int j = 0; j < 16; ++j) {
                float4 wv = wreg[j];
                #pragma unroll
                for (int p = 0; p < L; ++p) {
                    float4 h = hs4[p * 64 + kq * 16 + j];   // uniform broadcast
                    acc[p] = fmaf(wv.x, h.x, fmaf(wv.y, h.y,
                             fmaf(wv.z, h.z, fmaf(wv.w, h.w, acc[p]))));
                }
            }
            #pragma unroll
            for (int p = 0; p < L; ++p) ps[p * DD + kq * 64 + w] = acc[p];
            __syncthreads();

            if (tid < 32 * L) {
                const int p  = tid >> 5;
                const int c2 = tid & 15;
                const int q  = tid >> 4;
                float g0 = 0.f, g1 = 0.f, g2 = 0.f, g3 = 0.f;
                #pragma unroll
                for (int k = 0; k < 4; ++k) {
                    const float* pp = ps + p * DD + k * 64;
                    g0 += pp[ 0 + c2]; g1 += pp[16 + c2];
                    g2 += pp[32 + c2]; g3 += pp[48 + c2];
                }
                float gi = g0 + xnv[s - 1][0];
                float gf = g1 + xnv[s - 1][1];
                float gg = g2 + xnv[s - 1][2];
                float go = g3 + xnv[s - 1][3];
                float cin = cbuf[((s - 1) & 1) * 128 + p * 16 + c2];
                float cn  = sigf(gf) * cin + sigf(gi) * tanh_f(gg);
                float hn  = sigf(go) * tanh_f(cn);
                if (s < 4) {
                    cbuf[(s & 1) * 128 + q * 16 + c2] = cn;
                    co_store(hout[s - 1] + (size_t)(t * 2 * L + q) * DD
                                         + dt * 16 + c2, hn);
                } else {
                    co_store(h4g + (size_t)(t * NL + q) * DD
                                 + dt * 16 + c2, hn);
                }
            }

            // drain this block's stores, then RELEASE-signal (L2 wb precedes)
            __syncthreads();
            if (tid == 0) {
                if (s < 4) rel_add(&g_tf[s - 1][t][dt]);
                else       rel_add(&g_h4f[t]);
            }
        }
    } else if (bid < 416) {
        // ================= NODEPROJ =================
        float4* es4 = (float4*)smem;       // 20 x 65 float4
        float*  ps  = smem + 5200;         // 20 x 256 partials

        const int nb  = bid - 160;
        const int nt  = nb & 15;
        const int mt  = nb >> 4;
        const int kq  = tid >> 6;
        const int w   = tid & 63;

        const float4* W4 = (const float4*)Wih + (size_t)(nt * 64 + w) * 64 + kq * 16;
        float4 wr[16];
        #pragma unroll
        for (int j = 0; j < 16; ++j) wr[j] = W4[j];

        const float4* emb4 = (const float4*)emb;
        #pragma unroll
        for (int r = 0; r < 5; ++r) {
            int idx = tid + 256 * r;
            int m = idx >> 6, q = idx & 63;
            int n = mt * 20 + m;
            es4[m * 65 + q] = (n < NNODES) ? emb4[(size_t)n * 64 + q]
                                           : make_float4(0.f, 0.f, 0.f, 0.f);
        }
        __syncthreads();

        float acc[20];
        #pragma unroll
        for (int m = 0; m < 20; ++m) acc[m] = 0.f;
        #pragma unroll
        for (int j = 0; j < 16; ++j) {
            float4 wv = wr[j];
            #pragma unroll
            for (int m = 0; m < 20; ++m) {
                float4 h = es4[m * 65 + kq * 16 + j];
                acc[m] = fmaf(wv.x, h.x, fmaf(wv.y, h.y,
                         fmaf(wv.z, h.z, fmaf(wv.w, h.w, acc[m]))));
            }
        }
        #pragma unroll
        for (int m = 0; m < 20; ++m) ps[(m * 4 + kq) * 64 + w] = acc[m];
        __syncthreads();

        const int nl   = tid & 63;
        const int msub = tid >> 6;
        const int j    = nt * 64 + nl;
        const float bsum = bih[j] + bhh[j];
        #pragma unroll
        for (int r = 0; r < 5; ++r) {
            int m = msub * 5 + r;
            int n = mt * 20 + m;
            float s = ps[(m * 4 + 0) * 64 + nl] + ps[(m * 4 + 1) * 64 + nl]
                    + ps[(m * 4 + 2) * 64 + nl] + ps[(m * 4 + 3) * 64 + nl];
            if (n < NNODES) co_store(&xg[(size_t)n * G4 + j], s + bsum);
        }
        __syncthreads();                   // all waves' stores drained
        if (tid == 0) rel_add(&g_xgf[nt]); // L2 writeback precedes the bump
    } else {
        // ================= SCATTER =================
        float* cls  = smem;                // 160 x 16 cross slice
        int*   leafs = (int*)(smem + 2560);

        const int sb = bid - 416;
        const size_t r0 = (size_t)sb * 160;

        unsigned G = 0;
        if (tid < 64) G = flag_load(&g_sgen[sb]);
        if (tid == 0)
            __hip_atomic_fetch_add(&g_sgen[sb], 1u,
                __ATOMIC_RELAXED, __HIP_MEMORY_SCOPE_AGENT);

        // stage cross + argmax (overlaps the whole LSTM phase)
        #pragma unroll
        for (int k = 0; k < 10; ++k)
            cls[tid + 256 * k] = cross[r0 * 16 + tid + 256 * k];
        __syncthreads();
        if (tid < 160) {
            int leaf = 0;
            #pragma unroll
            for (int l = 15; l >= 0; --l)
                if (cls[tid * 16 + l] > 0.5f) leaf = l;
            int r = (int)(r0 + (size_t)tid);
            int b = r / NT;
            int t = r - b * NT;
            leafs[tid] = t * 16 + leaf;
        }

        // wait for all trees' h4
        if (tid < 64) {
            const unsigned tgt = 16u * (G + 1u);
            for (;;) {
                bool ok = true;
                if (tid < NT)
                    ok = (int)(flag_load(&g_h4f[tid]) - tgt) >= 0;
                if (__all(ok)) break;
                __builtin_amdgcn_s_sleep(2);
            }
        }
        __syncthreads();
        acq_fence();                       // h4 now safe to read

        // gather h4 rows -> 40MB coalesced out write
        const int lane = tid & 63;
        const int sub  = tid >> 6;
        float4* o4 = (float4*)out;
        #pragma unroll
        for (int batch = 0; batch < 5; ++batch) {
            unsigned long long a[8], b[8];
            #pragma unroll
            for (int i = 0; i < 8; ++i) {
                int rr = (batch * 8 + i) * 4 + sub;
                const unsigned long long* hr =
                    (const unsigned long long*)h4g
                    + (size_t)leafs[rr] * 128 + lane * 2;
                a[i] = co_load64(hr);
                b[i] = co_load64(hr + 1);
            }
            #pragma unroll
            for (int i = 0; i < 8; ++i) {
                int rr = (batch * 8 + i) * 4 + sub;
                union { unsigned long long u[2]; float4 f; } cv;
                cv.u[0] = a[i]; cv.u[1] = b[i];
                o4[(r0 + rr) * 64 + lane] = cv.f;
            }
        }
    }
}

// ---------------------------------------------------------------------------
extern "C" void kernel_launch(void* const* d_in, const int* in_sizes, int n_in,
                              void* d_out, int out_size, void* d_ws, size_t ws_size,
                              hipStream_t stream)
{
    const float* cross = (const float*)d_in[0];
    const float* emb   = (const float*)d_in[1];
    const float* Wih   = (const float*)d_in[2];
    const float* Whh   = (const float*)d_in[3];
    const float* bih   = (const float*)d_in[4];
    const float* bhh   = (const float*)d_in[5];
    float* out = (float*)d_out;

    float* ws = (float*)d_ws;
    float* xg = ws;                          // 310*1024
    float* h1 = xg + (size_t)NNODES * G4;    // 20*256
    float* h2 = h1 + 20 * DD;                // 40*256
    float* h3 = h2 + 40 * DD;                // 80*256
    float* h4 = h3 + 80 * DD;                // 160*256

    hipLaunchKernelGGL(k_fused, dim3(672), dim3(256), 0, stream,
                       cross, emb, Wih, Whh, bih, bhh,
                       xg, h1, h2, h3, h4, out);
}

// Round 6
// 125.018 us; speedup vs baseline: 1.2527x; 1.2527x over previous
//
#include <hip/hip_runtime.h>

#define NT 10          // trees
#define NL 16          // leaves per tree
#define NN 31          // nodes per tree
#define DD 256         // hidden dim
#define G4 1024        // 4*D gates
#define NNODES (NT*NN) // 310
#define NPATH (NT*NL)  // 160
#define NB 4096

// Monotone per-(step,tree) arrival counters (zero-init at load; __device__
// space survives ws poison; +16 per launch). Base is read at entry from the
// LAST step's flag (cannot advance until every block of the tree passed the
// earlier barriers -> entry-stable, launch-generation-free, replay-safe).
//
// Protocol hardening (R4/R5 lessons):
//  * producer: co_store data -> __syncthreads (per-wave vmcnt drain) ->
//    tid0 RELEASE fetch_add (L2 writeback precedes flag at MALL).
//  * consumer: tid0 polls with CAS (an RMW resolves at the coherence point;
//    a plain agent atomic LOAD can be served STALE by the non-coherent
//    per-XCD L2 until chance eviction — the measured ~12us/sync) ->
//    __syncthreads -> ACQUIRE fence (L1/L2 inv) -> data loads.
// ---------------------------------------------------------------------------
__device__ unsigned g_tf[3][NT][32];

__device__ __forceinline__ float sigf(float x)   { return 1.0f / (1.0f + __expf(-x)); }
__device__ __forceinline__ float tanh_f(float x) { return 2.0f / (1.0f + __expf(-2.0f*x)) - 1.0f; }

__device__ __forceinline__ void co_store(float* p, float v) {
    union { float f; unsigned u; } c; c.f = v;
    __hip_atomic_store((unsigned*)p, c.u, __ATOMIC_RELAXED, __HIP_MEMORY_SCOPE_AGENT);
}
__device__ __forceinline__ unsigned long long co_load64(const unsigned long long* p) {
    return __hip_atomic_load(p, __ATOMIC_RELAXED, __HIP_MEMORY_SCOPE_AGENT);
}
// CAS with impossible expected value == coherent read-current. Unlike
// fetch_add(0), the compiler cannot legally fold a CAS into a plain load.
__device__ __forceinline__ unsigned cas_read(unsigned* p) {
    unsigned exp = 0xFFFFFFFFu;
    __hip_atomic_compare_exchange_strong(p, &exp, 0xFFFFFFFFu,
        __ATOMIC_RELAXED, __ATOMIC_RELAXED, __HIP_MEMORY_SCOPE_AGENT);
    return exp;
}
__device__ __forceinline__ void rel_add(unsigned* p) {
    __hip_atomic_fetch_add(p, 1u, __ATOMIC_RELEASE, __HIP_MEMORY_SCOPE_AGENT);
}
__device__ __forceinline__ void acq_fence() {
    __builtin_amdgcn_fence(__ATOMIC_ACQUIRE, "agent");
}

// ---------------------------------------------------------------------------
// K1: nodeproj. xg[n][j] = emb[n].Wih[j] + bih[j] + bhh[j]
// 256 blocks = (mt 0..15 [20 nodes]) x (nt 0..15 [64 W rows]). Proven ~3 us.
// Plain stores; the launch boundary publishes xg to K2.
// ---------------------------------------------------------------------------
__global__ __launch_bounds__(256) void k_nodeproj(
    const float* __restrict__ emb, const float* __restrict__ Wih,
    const float* __restrict__ bih, const float* __restrict__ bhh,
    float* __restrict__ xg)
{
    __shared__ float smem[20 * 260 + 20 * 4 * 64];
    float4* es4 = (float4*)smem;
    float*  ps  = smem + 20 * 260;

    const int tid = threadIdx.x;
    const int nt  = blockIdx.x & 15;
    const int mt  = blockIdx.x >> 4;
    const int kq  = tid >> 6;
    const int w   = tid & 63;

    const float4* W4 = (const float4*)Wih + (size_t)(nt * 64 + w) * 64 + kq * 16;
    float4 wr[16];
    #pragma unroll
    for (int j = 0; j < 16; ++j) wr[j] = W4[j];

    const float4* emb4 = (const float4*)emb;
    #pragma unroll
    for (int r = 0; r < 5; ++r) {
        int idx = tid + 256 * r;                  // 0..1279
        int m = idx >> 6, q = idx & 63;
        int n = mt * 20 + m;
        es4[m * 65 + q] = (n < NNODES) ? emb4[(size_t)n * 64 + q]
                                       : make_float4(0.f, 0.f, 0.f, 0.f);
    }
    __syncthreads();

    float acc[20];
    #pragma unroll
    for (int m = 0; m < 20; ++m) acc[m] = 0.f;
    #pragma unroll
    for (int j = 0; j < 16; ++j) {
        float4 wv = wr[j];
        #pragma unroll
        for (int m = 0; m < 20; ++m) {
            float4 h = es4[m * 65 + kq * 16 + j];
            acc[m] = fmaf(wv.x, h.x, fmaf(wv.y, h.y,
                     fmaf(wv.z, h.z, fmaf(wv.w, h.w, acc[m]))));
        }
    }
    #pragma unroll
    for (int m = 0; m < 20; ++m) ps[(m * 4 + kq) * 64 + w] = acc[m];
    __syncthreads();

    const int nl   = tid & 63;
    const int msub = tid >> 6;
    const int j    = nt * 64 + nl;
    const float bsum = bih[j] + bhh[j];
    #pragma unroll
    for (int r = 0; r < 5; ++r) {
        int m = msub * 5 + r;
        int n = mt * 20 + m;
        float s = ps[(m * 4 + 0) * 64 + nl] + ps[(m * 4 + 1) * 64 + nl]
                + ps[(m * 4 + 2) * 64 + nl] + ps[(m * 4 + 3) * 64 + nl];
        if (n < NNODES) xg[(size_t)n * G4 + j] = s + bsum;
    }
}

// ---------------------------------------------------------------------------
// K2: all 4 LSTM steps, tree-structured (R2 structure, hardened sync).
// Grid: 160 blocks = 10 trees x 16 dtiles. Block (t,dt) owns 16 d-cols
// (64 W_hh rows register-stationary all steps). Step s consumes 2^(s-1)
// h rows, spawns 2^s. c never crosses blocks (LDS ping-pong). 3 in-kernel
// syncs (h1,h2,h3) with CAS-poll / release-add / acquire-fence.
// ---------------------------------------------------------------------------
__global__ __launch_bounds__(256) void k_treesteps(
    const float* __restrict__ xg, const float* __restrict__ Whh,
    float* __restrict__ h1g, float* __restrict__ h2g,
    float* __restrict__ h3g, float* __restrict__ h4g)
{
    __shared__ float hs[8 * DD];       // input h rows (full width), max L=8
    __shared__ float ps[8 * DD];       // GEMM partials (4 quarters x 64)
    __shared__ float cbuf[2][8 * 16];  // c ping-pong, this block's 16 cols

    const int tid  = threadIdx.x;
    const int t    = blockIdx.x >> 4;  // tree
    const int dt   = blockIdx.x & 15;  // d-tile
    const int kq   = tid >> 6;         // reduction quarter
    const int w    = tid & 63;
    const int gate = w >> 4;
    const int col  = w & 15;

    // Entry-stable base (first touch of this line this launch -> coherent;
    // CAS anyway for belt-and-braces).
    unsigned base = 0;
    if (tid == 0) base = cas_read(&g_tf[2][t][0]);

    // ---- Entry prefetch #1: W_hh quarter-rows (stationary all 4 steps)
    const float4* W4 = (const float4*)Whh
        + (size_t)(gate * DD + dt * 16 + col) * 64 + kq * 16;
    float4 wreg[16];
    #pragma unroll
    for (int j = 0; j < 16; ++j) wreg[j] = W4[j];

    // ---- Entry prefetch #2: xn gate biases for steps 1..4.
    float xnv[4][4];
    #pragma unroll
    for (int s = 1; s <= 4; ++s) {
        xnv[s-1][0] = xnv[s-1][1] = xnv[s-1][2] = xnv[s-1][3] = 0.f;
        if (tid < (32 << (s - 1))) {
            int node = (1 << s) - 1 + (tid >> 4);
            const float* xn = xg + (size_t)(t * NN + node) * G4 + dt * 16 + (tid & 15);
            xnv[s-1][0] = xn[0];
            xnv[s-1][1] = xn[256];
            xnv[s-1][2] = xn[512];
            xnv[s-1][3] = xn[768];
        }
    }

    // ---- Root step: elementwise, full width (h(-1)=c(-1)=0), no GEMM.
    {
        const float* xr = xg + (size_t)(t * NN) * G4;
        float r_i = xr[tid], r_g = xr[512 + tid], r_o = xr[768 + tid];
        float c0 = sigf(r_i) * tanh_f(r_g);
        hs[tid]  = sigf(r_o) * tanh_f(c0);
        if ((tid >> 4) == dt) cbuf[0][tid & 15] = c0;
    }
    __syncthreads();

    float* hout[3] = { h1g, h2g, h3g };
    const float* hin[3] = { h1g, h2g, h3g };

    #pragma unroll
    for (int s = 1; s <= 4; ++s) {
        const int L = 1 << (s - 1);                // input rows per tree

        if (s > 1) {
            // tid0 CAS-polls the step-(s-1) counter (coherent RMW read);
            // other waves park at the barrier.
            if (tid == 0) {
                const unsigned tgt = base + 16u;
                while ((int)(cas_read(&g_tf[s - 2][t][0]) - tgt) < 0)
                    __builtin_amdgcn_s_sleep(4);
            }
            __syncthreads();
            acq_fence();                           // invalidate stale L1/L2
            // stage L rows x 256 floats = L*128 u64 into hs
            const unsigned long long* src =
                (const unsigned long long*)(hin[s - 2] + (size_t)t * L * DD);
            unsigned long long raw[4];
            #pragma unroll
            for (int r = 0; r < L / 2; ++r)
                raw[r] = co_load64(src + tid + 256 * r);
            float2* hs2 = (float2*)hs;
            #pragma unroll
            for (int r = 0; r < L / 2; ++r) {
                union { unsigned long long u; float2 f; } cv; cv.u = raw[r];
                hs2[tid + 256 * r] = cv.f;
            }
            __syncthreads();
        }

        // GEMM: acc[p] = <W_hh[row] quarter kq, h[p] quarter kq>
        const float4* hs4 = (const float4*)hs;
        float acc[8];
        #pragma unroll
        for (int p = 0; p < 8; ++p) acc[p] = 0.f;
        #pragma unroll
        for (int j = 0; j < 16; ++j) {
            float4 wv = wreg[j];
            #pragma unroll
            for (int p = 0; p < L; ++p) {
                float4 h = hs4[p * 64 + kq * 16 + j];     // uniform broadcast
                acc[p] = fmaf(wv.x, h.x, fmaf(wv.y, h.y,
                         fmaf(wv.z, h.z, fmaf(wv.w, h.w, acc[p]))));
            }
        }
        #pragma unroll
        for (int p = 0; p < L; ++p) ps[p * DD + kq * 64 + w] = acc[p];
        __syncthreads();

        // Epilogue: parent p spawns children q=2p,2p+1.
        if (tid < 32 * L) {
            const int p  = tid >> 5;
            const int c2 = tid & 15;
            const int q  = tid >> 4;               // child prefix, 0..2L-1
            float g0 = 0.f, g1 = 0.f, g2 = 0.f, g3 = 0.f;
            #pragma unroll
            for (int k = 0; k < 4; ++k) {
                const float* pp = ps + p * DD + k * 64;
                g0 += pp[ 0 + c2]; g1 += pp[16 + c2];
                g2 += pp[32 + c2]; g3 += pp[48 + c2];
            }
            float gi = g0 + xnv[s - 1][0];
            float gf = g1 + xnv[s - 1][1];
            float gg = g2 + xnv[s - 1][2];
            float go = g3 + xnv[s - 1][3];
            float cin = cbuf[(s - 1) & 1][p * 16 + c2];
            float cn  = sigf(gf) * cin + sigf(gi) * tanh_f(gg);
            float hn  = sigf(go) * tanh_f(cn);
            if (s < 4) {
                cbuf[s & 1][q * 16 + c2] = cn;
                co_store(hout[s - 1] + (size_t)(t * 2 * L + q) * DD
                                     + dt * 16 + c2, hn);
            } else {
                // launch boundary publishes h4 to the scatter kernel
                h4g[(size_t)(t * NL + q) * DD + dt * 16 + c2] = hn;
            }
        }

        if (s < 4) {
            // all waves' co_stores drained by the barrier, then RELEASE-add
            __syncthreads();
            if (tid == 0) rel_add(&g_tf[s - 1][t][0]);
        }
    }
}

// ---------------------------------------------------------------------------
// K3: scatter out[b,t,:] = h4[t*16 + argmax(cross[b,t,:]), :]
// 640 blocks x 64 rows: LDS-staged leaf argmax, then fat 16-iter row copy.
// ---------------------------------------------------------------------------
__global__ __launch_bounds__(256) void k_scatter(
    const float* __restrict__ cross, const float* __restrict__ htab,
    float* __restrict__ out)
{
    __shared__ float cls[1024];
    __shared__ int   leafs[64];
    const int tid = threadIdx.x;
    const size_t r0 = (size_t)blockIdx.x * 64;

    #pragma unroll
    for (int k = 0; k < 4; ++k)
        cls[tid + 256 * k] = cross[r0 * 16 + tid + 256 * k];
    __syncthreads();

    if (tid < 64) {
        int leaf = 0;
        #pragma unroll
        for (int l = 15; l >= 0; --l)
            if (cls[tid * 16 + l] > 0.5f) leaf = l;
        int r = (int)(r0 + (size_t)tid);
        int b = r / NT;
        int t = r - b * NT;
        leafs[tid] = t * 16 + leaf;
    }
    __syncthreads();

    const float4* h4 = (const float4*)htab;
    float4* o4 = (float4*)out;
    const int lane = tid & 63;
    const int sub  = tid >> 6;
    #pragma unroll
    for (int it = 0; it < 16; ++it) {
        int rr = it * 4 + sub;
        o4[(r0 + rr) * 64 + lane] = h4[(size_t)leafs[rr] * 64 + lane];
    }
}

// ---------------------------------------------------------------------------
extern "C" void kernel_launch(void* const* d_in, const int* in_sizes, int n_in,
                              void* d_out, int out_size, void* d_ws, size_t ws_size,
                              hipStream_t stream)
{
    const float* cross = (const float*)d_in[0];
    const float* emb   = (const float*)d_in[1];
    const float* Wih   = (const float*)d_in[2];
    const float* Whh   = (const float*)d_in[3];
    const float* bih   = (const float*)d_in[4];
    const float* bhh   = (const float*)d_in[5];
    float* out = (float*)d_out;

    float* ws = (float*)d_ws;
    float* xg = ws;                          // 310*1024
    float* h1 = xg + (size_t)NNODES * G4;    // 20*256
    float* h2 = h1 + 20 * DD;                // 40*256
    float* h3 = h2 + 40 * DD;                // 80*256
    float* h4 = h3 + 80 * DD;                // 160*256

    hipLaunchKernelGGL(k_nodeproj, dim3(256), dim3(256), 0, stream,
                       emb, Wih, bih, bhh, xg);
    hipLaunchKernelGGL(k_treesteps, dim3(160), dim3(256), 0, stream,
                       xg, Whh, h1, h2, h3, h4);
    hipLaunchKernelGGL(k_scatter, dim3(640), dim3(256), 0, stream,
                       cross, h4, out);
}

// Round 7
// 111.897 us; speedup vs baseline: 1.3996x; 1.1173x over previous
//
#include <hip/hip_runtime.h>

#define NT 10          // trees
#define NL 16          // leaves per tree
#define NN 31          // nodes per tree
#define DD 256         // hidden dim
#define G4 1024        // 4*D gates
#define NNODES (NT*NN) // 310
#define NPATH (NT*NL)  // 160
#define NB 4096

// Monotone per-(step,tree) arrival counters (zero-init at load; __device__
// space survives ws poison; +16 per launch each). Base is read at kernel
// entry from the LAST step's flag (cannot advance until every block of the
// tree passed the earlier barriers -> entry-stable, launch-generation-free,
// replay-safe; kernel-launch boundary guarantees entry reads are fresh).
// Protocol identical to the proven R2 kernel. The ONLY change this round:
// XCD-clustered block mapping so all 16 blocks of a tree share one L2 —
// flag updates and h rows become same-L2 (coherence-point) traffic instead
// of cross-XCD stale-until-eviction traffic.
__device__ unsigned g_tf[3][NT][32];

__device__ __forceinline__ float sigf(float x)   { return 1.0f / (1.0f + __expf(-x)); }
__device__ __forceinline__ float tanh_f(float x) { return 2.0f / (1.0f + __expf(-2.0f*x)) - 1.0f; }

__device__ __forceinline__ void co_store(float* p, float v) {
    union { float f; unsigned u; } c; c.f = v;
    __hip_atomic_store((unsigned*)p, c.u, __ATOMIC_RELAXED, __HIP_MEMORY_SCOPE_AGENT);
}

// ---------------------------------------------------------------------------
// K1: nodeproj. xg[n][j] = emb[n].Wih[j] + bih[j] + bhh[j]
// 256 blocks = (mt 0..15 [20 nodes]) x (nt 0..15 [64 W rows]). Proven ~3 us.
// Plain stores; the launch boundary publishes xg to K2.
// ---------------------------------------------------------------------------
__global__ __launch_bounds__(256) void k_nodeproj(
    const float* __restrict__ emb, const float* __restrict__ Wih,
    const float* __restrict__ bih, const float* __restrict__ bhh,
    float* __restrict__ xg)
{
    __shared__ float smem[20 * 260 + 20 * 4 * 64];
    float4* es4 = (float4*)smem;
    float*  ps  = smem + 20 * 260;

    const int tid = threadIdx.x;
    const int nt  = blockIdx.x & 15;
    const int mt  = blockIdx.x >> 4;
    const int kq  = tid >> 6;
    const int w   = tid & 63;

    const float4* W4 = (const float4*)Wih + (size_t)(nt * 64 + w) * 64 + kq * 16;
    float4 wr[16];
    #pragma unroll
    for (int j = 0; j < 16; ++j) wr[j] = W4[j];

    const float4* emb4 = (const float4*)emb;
    #pragma unroll
    for (int r = 0; r < 5; ++r) {
        int idx = tid + 256 * r;                  // 0..1279
        int m = idx >> 6, q = idx & 63;
        int n = mt * 20 + m;
        es4[m * 65 + q] = (n < NNODES) ? emb4[(size_t)n * 64 + q]
                                       : make_float4(0.f, 0.f, 0.f, 0.f);
    }
    __syncthreads();

    float acc[20];
    #pragma unroll
    for (int m = 0; m < 20; ++m) acc[m] = 0.f;
    #pragma unroll
    for (int j = 0; j < 16; ++j) {
        float4 wv = wr[j];
        #pragma unroll
        for (int m = 0; m < 20; ++m) {
            float4 h = es4[m * 65 + kq * 16 + j];
            acc[m] = fmaf(wv.x, h.x, fmaf(wv.y, h.y,
                     fmaf(wv.z, h.z, fmaf(wv.w, h.w, acc[m]))));
        }
    }
    #pragma unroll
    for (int m = 0; m < 20; ++m) ps[(m * 4 + kq) * 64 + w] = acc[m];
    __syncthreads();

    const int nl   = tid & 63;
    const int msub = tid >> 6;
    const int j    = nt * 64 + nl;
    const float bsum = bih[j] + bhh[j];
    #pragma unroll
    for (int r = 0; r < 5; ++r) {
        int m = msub * 5 + r;
        int n = mt * 20 + m;
        float s = ps[(m * 4 + 0) * 64 + nl] + ps[(m * 4 + 1) * 64 + nl]
                + ps[(m * 4 + 2) * 64 + nl] + ps[(m * 4 + 3) * 64 + nl];
        if (n < NNODES) xg[(size_t)n * G4 + j] = s + bsum;
    }
}

// ---------------------------------------------------------------------------
// K2: all 4 LSTM steps, tree-structured, XCD-CLUSTERED.
// Grid 256 (96 early-exit). bid%8 = XCD (empirical round-robin dispatch):
//   k = bid>>3:  k<16       -> tree t = bid&7      (XCDs 0..7), dt = k
//                k>=16,xcd<2 -> tree t = 8 + (bid&7) (XCDs 0..1), dt = k-16
//                else exit
// All 16 blocks of a tree live on ONE XCD -> their flag polls and h loads
// are serviced by the same L2 (their common coherence point) instead of
// waiting for chance eviction of stale cross-XCD lines. 32 blocks/XCD =
// 1 block/CU. Protocol, math, and layout byte-identical to R2.
// ---------------------------------------------------------------------------
__global__ __launch_bounds__(256) void k_treesteps(
    const float* __restrict__ xg, const float* __restrict__ Whh,
    float* __restrict__ h1g, float* __restrict__ h2g,
    float* __restrict__ h3g, float* __restrict__ h4g)
{
    __shared__ float hs[8 * DD];       // input h rows (full width), max L=8
    __shared__ float ps[8 * DD];       // GEMM partials (4 quarters x 64)
    __shared__ float cbuf[2][8 * 16];  // c ping-pong, this block's 16 cols

    const int bid = blockIdx.x;
    const int xcd = bid & 7;
    const int k   = bid >> 3;          // 0..31
    int t, dt;
    if (k < 16)        { t = xcd;     dt = k; }
    else if (xcd < 2)  { t = 8 + xcd; dt = k - 16; }
    else return;

    const int tid  = threadIdx.x;
    const int kq   = tid >> 6;         // reduction quarter
    const int w    = tid & 63;
    const int gate = w >> 4;
    const int col  = w & 15;

    // Entry-stable base (fresh at kernel entry; see decl note).
    const unsigned base = __hip_atomic_load(&g_tf[2][t][0],
        __ATOMIC_RELAXED, __HIP_MEMORY_SCOPE_AGENT);

    // ---- Entry prefetch #1: W_hh quarter-rows (stationary all 4 steps)
    const float4* W4 = (const float4*)Whh
        + (size_t)(gate * DD + dt * 16 + col) * 64 + kq * 16;
    float4 wreg[16];
    #pragma unroll
    for (int j = 0; j < 16; ++j) wreg[j] = W4[j];

    // ---- Entry prefetch #2: xn gate biases for steps 1..4.
    float xnv[4][4];
    #pragma unroll
    for (int s = 1; s <= 4; ++s) {
        xnv[s-1][0] = xnv[s-1][1] = xnv[s-1][2] = xnv[s-1][3] = 0.f;
        if (tid < (32 << (s - 1))) {
            int node = (1 << s) - 1 + (tid >> 4);
            const float* xn = xg + (size_t)(t * NN + node) * G4 + dt * 16 + (tid & 15);
            xnv[s-1][0] = xn[0];
            xnv[s-1][1] = xn[256];
            xnv[s-1][2] = xn[512];
            xnv[s-1][3] = xn[768];
        }
    }

    // ---- Root step: elementwise, full width (h(-1)=c(-1)=0), no GEMM.
    {
        const float* xr = xg + (size_t)(t * NN) * G4;
        float r_i = xr[tid], r_g = xr[512 + tid], r_o = xr[768 + tid];
        float c0 = sigf(r_i) * tanh_f(r_g);
        hs[tid]  = sigf(r_o) * tanh_f(c0);
        if ((tid >> 4) == dt) cbuf[0][tid & 15] = c0;
    }
    __syncthreads();

    float* hout[3] = { h1g, h2g, h3g };
    const float* hin[3] = { h1g, h2g, h3g };

    #pragma unroll
    for (int s = 1; s <= 4; ++s) {
        const int L = 1 << (s - 1);                // input rows per tree

        if (s > 1) {
            // wait for step-(s-1) h rows from all 16 blocks of this tree
            if (tid < 64) {
                const unsigned tgt = base + 16u;
                while (__hip_atomic_load(&g_tf[s - 2][t][0],
                        __ATOMIC_RELAXED, __HIP_MEMORY_SCOPE_AGENT) < tgt)
                    __builtin_amdgcn_s_sleep(2);
            }
            __syncthreads();
            // stage L rows x 256 floats = L*128 u64 into hs
            const unsigned long long* src =
                (const unsigned long long*)(hin[s - 2] + (size_t)t * L * DD);
            unsigned long long raw[4];
            #pragma unroll
            for (int r = 0; r < L / 2; ++r)
                raw[r] = __hip_atomic_load(src + tid + 256 * r,
                    __ATOMIC_RELAXED, __HIP_MEMORY_SCOPE_AGENT);
            float2* hs2 = (float2*)hs;
            #pragma unroll
            for (int r = 0; r < L / 2; ++r) {
                union { unsigned long long u; float2 f; } cv; cv.u = raw[r];
                hs2[tid + 256 * r] = cv.f;
            }
            __syncthreads();
        }

        // GEMM: acc[p] = <W_hh[row] quarter kq, h[p] quarter kq>
        const float4* hs4 = (const float4*)hs;
        float acc[8];
        #pragma unroll
        for (int p = 0; p < 8; ++p) acc[p] = 0.f;
        #pragma unroll
        for (int j = 0; j < 16; ++j) {
            float4 wv = wreg[j];
            #pragma unroll
            for (int p = 0; p < L; ++p) {
                float4 h = hs4[p * 64 + kq * 16 + j];     // uniform broadcast
                acc[p] = fmaf(wv.x, h.x, fmaf(wv.y, h.y,
                         fmaf(wv.z, h.z, fmaf(wv.w, h.w, acc[p]))));
            }
        }
        #pragma unroll
        for (int p = 0; p < L; ++p) ps[p * DD + kq * 64 + w] = acc[p];
        __syncthreads();

        // Epilogue: parent p spawns children q=2p,2p+1.
        if (tid < 32 * L) {
            const int p  = tid >> 5;
            const int c2 = tid & 15;
            const int q  = tid >> 4;               // child prefix, 0..2L-1
            float g0 = 0.f, g1 = 0.f, g2 = 0.f, g3 = 0.f;
            #pragma unroll
            for (int kk = 0; kk < 4; ++kk) {
                const float* pp = ps + p * DD + kk * 64;
                g0 += pp[ 0 + c2]; g1 += pp[16 + c2];
                g2 += pp[32 + c2]; g3 += pp[48 + c2];
            }
            float gi = g0 + xnv[s - 1][0];
            float gf = g1 + xnv[s - 1][1];
            float gg = g2 + xnv[s - 1][2];
            float go = g3 + xnv[s - 1][3];
            float cin = cbuf[(s - 1) & 1][p * 16 + c2];
            float cn  = sigf(gf) * cin + sigf(gi) * tanh_f(gg);
            float hn  = sigf(go) * tanh_f(cn);
            if (s < 4) {
                cbuf[s & 1][q * 16 + c2] = cn;
                co_store(hout[s - 1] + (size_t)(t * 2 * L + q) * DD
                                     + dt * 16 + c2, hn);
            } else {
                // launch boundary publishes h4 to the scatter kernel
                h4g[(size_t)(t * NL + q) * DD + dt * 16 + c2] = hn;
            }
        }

        if (s < 4) {
            // drain this block's coherent h stores, then signal arrival
            __syncthreads();
            if (tid == 0)
                __hip_atomic_fetch_add(&g_tf[s - 1][t][0], 1u,
                    __ATOMIC_RELAXED, __HIP_MEMORY_SCOPE_AGENT);
        }
    }
}

// ---------------------------------------------------------------------------
// K3: scatter out[b,t,:] = h4[t*16 + argmax(cross[b,t,:]), :]
// One wave per (b,t) row (40960 waves): ballot -> leaf, float4 row copy.
// (R2's proven version.)
// ---------------------------------------------------------------------------
__global__ __launch_bounds__(256) void k_scatter(
    const float* __restrict__ cross, const float* __restrict__ htab,
    float* __restrict__ out)
{
    const int tid  = threadIdx.x;
    const int wave = tid >> 6;
    const int lane = tid & 63;
    const int r = blockIdx.x * 4 + wave;     // 0..40959 = b*10 + t
    const int b = r / NT;
    const int t = r - b * NT;

    float v = 0.f;
    if (lane < NL) v = cross[(size_t)b * (NT * NL) + t * NL + lane];
    unsigned long long m = __ballot(v > 0.5f);
    int leaf = m ? (int)__builtin_ctzll(m) : 0;
    int p = t * NL + leaf;

    const float4* h4 = (const float4*)htab;
    float4* o4 = (float4*)out;
    o4[(size_t)r * 64 + lane] = h4[(size_t)p * 64 + lane];
}

// ---------------------------------------------------------------------------
extern "C" void kernel_launch(void* const* d_in, const int* in_sizes, int n_in,
                              void* d_out, int out_size, void* d_ws, size_t ws_size,
                              hipStream_t stream)
{
    const float* cross = (const float*)d_in[0];
    const float* emb   = (const float*)d_in[1];
    const float* Wih   = (const float*)d_in[2];
    const float* Whh   = (const float*)d_in[3];
    const float* bih   = (const float*)d_in[4];
    const float* bhh   = (const float*)d_in[5];
    float* out = (float*)d_out;

    float* ws = (float*)d_ws;
    float* xg = ws;                          // 310*1024
    float* h1 = xg + (size_t)NNODES * G4;    // 20*256
    float* h2 = h1 + 20 * DD;                // 40*256
    float* h3 = h2 + 40 * DD;                // 80*256
    float* h4 = h3 + 80 * DD;                // 160*256

    hipLaunchKernelGGL(k_nodeproj, dim3(256), dim3(256), 0, stream,
                       emb, Wih, bih, bhh, xg);
    hipLaunchKernelGGL(k_treesteps, dim3(256), dim3(256), 0, stream,
                       xg, Whh, h1, h2, h3, h4);
    hipLaunchKernelGGL(k_scatter, dim3(10240), dim3(256), 0, stream,
                       cross, h4, out);
}

// Round 9
// 105.738 us; speedup vs baseline: 1.4812x; 1.0582x over previous
//
#include <hip/hip_runtime.h>

#define NT 10          // trees
#define NL 16          // leaves per tree
#define NN 31          // nodes per tree
#define DD 256         // hidden dim
#define G4 1024        // 4*D gates
#define NB 4096

// Per-block private launch-generation counters (zero-init at module load;
// __device__ space survives ws poison). Block (t,dt) alone reads+bumps its
// word at entry: read-before-bump => G = #completed launches, identical
// across all blocks of a launch, dispatch-order- and graph-replay-safe.
// tag = G+1 (1,2,3,...) can never equal ws-poison 0xAAAAAAAA.
__device__ unsigned g_gen[NT * 16];

__device__ __forceinline__ float sigf(float x)   { return 1.0f / (1.0f + __expf(-x)); }
__device__ __forceinline__ float tanh_f(float x) { return 2.0f / (1.0f + __expf(-2.0f*x)) - 1.0f; }

// Gen-tagged word publish/poll: the datum and its readiness flag are ONE
// aligned 8-byte atomic word => no drain-before-signal, no release/acquire,
// no flag round. Sync cost = a single store->load visibility hop.
__device__ __forceinline__ void pub64(unsigned long long* p, unsigned tag, float v) {
    union { float f; unsigned u; } c; c.f = v;
    __hip_atomic_store(p, ((unsigned long long)tag << 32) | c.u,
                       __ATOMIC_RELAXED, __HIP_MEMORY_SCOPE_AGENT);
}
__device__ __forceinline__ unsigned long long ld64(const unsigned long long* p) {
    return __hip_atomic_load(p, __ATOMIC_RELAXED, __HIP_MEMORY_SCOPE_AGENT);
}

// ---------------------------------------------------------------------------
// K1: whole tree-LSTM in one launch, 160 blocks = 10 trees x 16 d-tiles.
// Block (t,dt) holds BOTH W_ih and W_hh quarter-rows for its 64 gate-rows
// (gate*256 + dt*16 + col) register-stationary. Phases:
//   entry : W regs, emb[t] -> LDS, bias slice, gen tag
//   xproj : all 31 nodes' x-gate slices (emb.Wih + bias) -> LDS xsl
//           (same fmaf chain/fold order as the old nodeproj => bit-identical)
//           [R8 bug fixed here: the fold needs TWO 256-thread passes to
//            cover 8 nodes x 64 cols = 512 slots; R8 wrote only 4 nodes]
//   root  : own 16 cols of c0/h0 from xsl[0]; publish h0 slice (gen-tagged)
//   s=1..4: poll-stage full h rows -> LDS, GEMM vs W_hh, epilogue gates;
//           publish child h slices gen-tagged (s<4) / plain h4 store (s=4,
//           launch boundary publishes to scatter).
// Cross-block data is exclusively gen-tagged words: no flags, no fences.
// ---------------------------------------------------------------------------
__global__ __launch_bounds__(256) void k_treelstm(
    const float* __restrict__ emb, const float* __restrict__ Wih,
    const float* __restrict__ Whh, const float* __restrict__ bih,
    const float* __restrict__ bhh,
    unsigned long long* __restrict__ hx0, unsigned long long* __restrict__ hx1,
    unsigned long long* __restrict__ hx2, unsigned long long* __restrict__ hx3,
    float* __restrict__ h4g)
{
    __shared__ float es [NN * DD];     // 31 emb rows (tree-local)
    __shared__ float ps [8 * DD];      // GEMM partials (4 quarters x 64)
    __shared__ float xsl[NN * 64];     // x-gate slices incl. bias
    __shared__ float hs [8 * DD];      // staged input h rows
    __shared__ float cbuf[2 * 128];    // c ping-pong (block's 16 cols)
    __shared__ float bsl[64];
    __shared__ unsigned stag;

    const int tid  = threadIdx.x;
    const int t    = blockIdx.x >> 4;
    const int dt   = blockIdx.x & 15;
    const int kq   = tid >> 6;         // reduction quarter
    const int w    = tid & 63;         // owned gate-row within tile
    const int gate = w >> 4;
    const int col  = w & 15;
    const int grow = gate * DD + dt * 16 + col;

    if (tid == 0) {
        unsigned G = __hip_atomic_load(&g_gen[t * 16 + dt],
            __ATOMIC_RELAXED, __HIP_MEMORY_SCOPE_AGENT);
        __hip_atomic_store(&g_gen[t * 16 + dt], G + 1u,
            __ATOMIC_RELAXED, __HIP_MEMORY_SCOPE_AGENT);
        stag = G + 1u;
    }
    if (tid < 64) {
        int g2 = tid >> 4, c3 = tid & 15;
        int r2 = g2 * DD + dt * 16 + c3;
        bsl[tid] = bih[r2] + bhh[r2];
    }

    // ---- W_ih + W_hh quarter-rows -> registers (stationary)
    const float4* Wi4 = (const float4*)Wih + (size_t)grow * 64 + kq * 16;
    const float4* Wh4 = (const float4*)Whh + (size_t)grow * 64 + kq * 16;
    float4 wih[16], whh[16];
    #pragma unroll
    for (int j = 0; j < 16; ++j) { wih[j] = Wi4[j]; whh[j] = Wh4[j]; }

    // ---- emb tree rows -> LDS
    const float4* emb4 = (const float4*)emb + (size_t)t * NN * 64;
    float4* es4 = (float4*)es;
    #pragma unroll
    for (int r = 0; r < 8; ++r) {
        int idx = tid + 256 * r;                 // 0..2047, need < 1984
        if (idx < NN * 64) es4[idx] = emb4[idx];
    }
    __syncthreads();
    const unsigned tag = stag;

    // ---- xproj: xsl[n][w] = emb[n].Wih[grow] + bias, 4 batches of 8 nodes
    #pragma unroll
    for (int b4 = 0; b4 < 4; ++b4) {
        const int n0 = b4 * 8;
        const int nn = (b4 == 3) ? 7 : 8;
        float acc[8];
        #pragma unroll
        for (int m = 0; m < 8; ++m) acc[m] = 0.f;
        #pragma unroll
        for (int j = 0; j < 16; ++j) {
            float4 wv = wih[j];
            #pragma unroll
            for (int m = 0; m < 8; ++m) {
                if (m < nn) {
                    float4 h = es4[(n0 + m) * 64 + kq * 16 + j];
                    acc[m] = fmaf(wv.x, h.x, fmaf(wv.y, h.y,
                             fmaf(wv.z, h.z, fmaf(wv.w, h.w, acc[m]))));
                }
            }
        }
        #pragma unroll
        for (int m = 0; m < 8; ++m)
            if (m < nn) ps[m * DD + kq * 64 + w] = acc[m];
        __syncthreads();
        // fold: 8 nodes x 64 cols = 512 slots -> TWO 256-thread passes
        #pragma unroll
        for (int rep = 0; rep < 2; ++rep) {
            int idx = tid + 256 * rep;           // 0..511
            if (idx < nn * 64) {
                int m = idx >> 6, w2 = idx & 63;
                xsl[(n0 + m) * 64 + w2] =
                      ps[m * DD +   0 + w2] + ps[m * DD +  64 + w2]
                    + ps[m * DD + 128 + w2] + ps[m * DD + 192 + w2] + bsl[w2];
            }
        }
        __syncthreads();
    }

    // ---- root: own 16 cols of c0/h0; publish h0 slice; stage full h0
    if (tid < 16) {
        float xi  = xsl[ 0 + tid];
        float xgg = xsl[32 + tid];
        float xo  = xsl[48 + tid];
        float c0 = sigf(xi) * tanh_f(xgg);        // h(-1)=c(-1)=0
        float h0 = sigf(xo) * tanh_f(c0);
        cbuf[tid] = c0;
        pub64(hx0 + (size_t)t * DD + dt * 16 + tid, tag, h0);
    }
    {
        const unsigned long long* src = hx0 + (size_t)t * DD;
        unsigned long long v = ld64(src + tid);
        while ((unsigned)(v >> 32) != tag) {
            __builtin_amdgcn_s_sleep(1);
            v = ld64(src + tid);
        }
        union { unsigned u; float f; } cv; cv.u = (unsigned)v;
        hs[tid] = cv.f;
    }
    __syncthreads();

    const unsigned long long* hin[3] = { hx1, hx2, hx3 };
    unsigned long long* hout[3] = { hx1, hx2, hx3 };

    #pragma unroll
    for (int s = 1; s <= 4; ++s) {
        const int L = 1 << (s - 1);              // input rows per tree

        if (s > 1) {
            // poll-stage L full rows; per-thread per-word self-validating
            const unsigned long long* src = hin[s - 2] + (size_t)t * L * DD;
            unsigned long long v[8];
            #pragma unroll
            for (int r = 0; r < L; ++r) v[r] = ld64(src + tid + 256 * r);
            #pragma unroll
            for (int r = 0; r < L; ++r) {
                while ((unsigned)(v[r] >> 32) != tag) {
                    __builtin_amdgcn_s_sleep(1);
                    v[r] = ld64(src + tid + 256 * r);
                }
                union { unsigned u; float f; } cv; cv.u = (unsigned)v[r];
                hs[tid + 256 * r] = cv.f;
            }
            __syncthreads();
        }

        // GEMM: acc[p] = <W_hh[grow] quarter kq, h[p] quarter kq>
        const float4* hs4 = (const float4*)hs;
        float acc[8];
        #pragma unroll
        for (int p = 0; p < 8; ++p) acc[p] = 0.f;
        #pragma unroll
        for (int j = 0; j < 16; ++j) {
            float4 wv = whh[j];
            #pragma unroll
            for (int p = 0; p < L; ++p) {
                float4 h = hs4[p * 64 + kq * 16 + j];    // uniform broadcast
                acc[p] = fmaf(wv.x, h.x, fmaf(wv.y, h.y,
                         fmaf(wv.z, h.z, fmaf(wv.w, h.w, acc[p]))));
            }
        }
        #pragma unroll
        for (int p = 0; p < L; ++p) ps[p * DD + kq * 64 + w] = acc[p];
        __syncthreads();

        // Epilogue: parent p spawns children q=2p,2p+1
        if (tid < 32 * L) {
            const int p  = tid >> 5;
            const int c2 = tid & 15;
            const int q  = tid >> 4;             // child prefix, 0..2L-1
            float g0 = 0.f, g1 = 0.f, g2 = 0.f, g3 = 0.f;
            #pragma unroll
            for (int k = 0; k < 4; ++k) {
                const float* pp = ps + p * DD + k * 64;
                g0 += pp[ 0 + c2]; g1 += pp[16 + c2];
                g2 += pp[32 + c2]; g3 += pp[48 + c2];
            }
            const int node = (1 << s) - 1 + q;
            const float* xp = xsl + node * 64;
            float gi = g0 + xp[ 0 + c2];
            float gf = g1 + xp[16 + c2];
            float gg = g2 + xp[32 + c2];
            float go = g3 + xp[48 + c2];
            float cin = cbuf[((s - 1) & 1) * 128 + p * 16 + c2];
            float cn  = sigf(gf) * cin + sigf(gi) * tanh_f(gg);
            float hn  = sigf(go) * tanh_f(cn);
            if (s < 4) {
                cbuf[(s & 1) * 128 + q * 16 + c2] = cn;
                pub64(hout[s - 1] + (size_t)(t * 2 * L + q) * DD
                                  + dt * 16 + c2, tag, hn);
            } else {
                // launch boundary publishes h4 to the scatter kernel
                h4g[(size_t)(t * NL + q) * DD + dt * 16 + c2] = hn;
            }
        }
        // no trailing barrier needed: next staging writes only hs (disjoint
        // from ps/xsl/cbuf), and its post-staging barrier orders everything.
    }
}

// ---------------------------------------------------------------------------
// K2: scatter out[b,t,:] = h4[t*16 + argmax(cross[b,t,:]), :]
// One wave per (b,t) row (40960 waves): ballot -> leaf, float4 row copy.
// (Proven R2 version.)
// ---------------------------------------------------------------------------
__global__ __launch_bounds__(256) void k_scatter(
    const float* __restrict__ cross, const float* __restrict__ htab,
    float* __restrict__ out)
{
    const int tid  = threadIdx.x;
    const int wave = tid >> 6;
    const int lane = tid & 63;
    const int r = blockIdx.x * 4 + wave;     // 0..40959 = b*10 + t
    const int b = r / NT;
    const int t = r - b * NT;

    float v = 0.f;
    if (lane < NL) v = cross[(size_t)b * (NT * NL) + t * NL + lane];
    unsigned long long m = __ballot(v > 0.5f);
    int leaf = m ? (int)__builtin_ctzll(m) : 0;
    int p = t * NL + leaf;

    const float4* h4 = (const float4*)htab;
    float4* o4 = (float4*)out;
    o4[(size_t)r * 64 + lane] = h4[(size_t)p * 64 + lane];
}

// ---------------------------------------------------------------------------
extern "C" void kernel_launch(void* const* d_in, const int* in_sizes, int n_in,
                              void* d_out, int out_size, void* d_ws, size_t ws_size,
                              hipStream_t stream)
{
    const float* cross = (const float*)d_in[0];
    const float* emb   = (const float*)d_in[1];
    const float* Wih   = (const float*)d_in[2];
    const float* Whh   = (const float*)d_in[3];
    const float* bih   = (const float*)d_in[4];
    const float* bhh   = (const float*)d_in[5];
    float* out = (float*)d_out;

    unsigned long long* hx0 = (unsigned long long*)d_ws;   // 10*256 u64
    unsigned long long* hx1 = hx0 + (size_t)NT * DD;       // 20*256
    unsigned long long* hx2 = hx1 + (size_t)2 * NT * DD;   // 40*256
    unsigned long long* hx3 = hx2 + (size_t)4 * NT * DD;   // 80*256
    float* h4g = (float*)(hx3 + (size_t)8 * NT * DD);      // 160*256 f32

    hipLaunchKernelGGL(k_treelstm, dim3(160), dim3(256), 0, stream,
                       emb, Wih, Whh, bih, bhh, hx0, hx1, hx2, hx3, h4g);
    hipLaunchKernelGGL(k_scatter, dim3(10240), dim3(256), 0, stream,
                       cross, h4g, out);
}

// Round 10
// 101.319 us; speedup vs baseline: 1.5458x; 1.0436x over previous
//
#include <hip/hip_runtime.h>

#define NT 10          // trees
#define NL 16          // leaves per tree
#define NN 31          // nodes per tree
#define DD 256         // hidden dim
#define NB 4096

// Per-block private launch-generation counters (zero-init at module load;
// __device__ space survives ws poison). Block (t,dt) alone reads+bumps its
// word at entry: read-before-bump => G = #completed launches, identical
// across all blocks of a launch, dispatch-order- and graph-replay-safe.
// tag = G+1 (1,2,3,...) can never equal ws-poison 0xAAAAAAAA.
__device__ unsigned g_gen[NT * 16];

__device__ __forceinline__ float sigf(float x)   { return 1.0f / (1.0f + __expf(-x)); }
__device__ __forceinline__ float tanh_f(float x) { return 2.0f / (1.0f + __expf(-2.0f*x)) - 1.0f; }

// Gen-tagged word publish/poll: datum + readiness in ONE aligned 8-byte
// atomic word => no flag round, no fences; cost = one visibility hop.
__device__ __forceinline__ void pub64(unsigned long long* p, unsigned tag, float v) {
    union { float f; unsigned u; } c; c.f = v;
    __hip_atomic_store(p, ((unsigned long long)tag << 32) | c.u,
                       __ATOMIC_RELAXED, __HIP_MEMORY_SCOPE_AGENT);
}
__device__ __forceinline__ unsigned long long ld64(const unsigned long long* p) {
    return __hip_atomic_load(p, __ATOMIC_RELAXED, __HIP_MEMORY_SCOPE_AGENT);
}

// ---------------------------------------------------------------------------
// K1: whole tree-LSTM, 160 blocks = 10 trees x 16 d-tiles (R9 structure).
// R10 change: the 31-node xproj is split into 5 batches INTERLEAVED with the
// exchange windows (publish earlier, stage later) so per-step straggler skew
// is absorbed by useful work instead of spin-waiting:
//   entry -> x[0] -> root+pub(h0) -> x[1..6] -> stage h0 -> s1 -> pub(h1)
//   -> x[7..14] -> stage h1 -> s2 -> pub(h2) -> x[15..22] -> stage h2 -> s3
//   -> pub(h3) -> x[23..30] -> stage h3 -> s4 -> h4 store.
// Math/indices byte-identical to R9; added barrier at batch entry protects
// ps from the preceding epilogue's reads.
// ---------------------------------------------------------------------------
__global__ __launch_bounds__(256) void k_treelstm(
    const float* __restrict__ emb, const float* __restrict__ Wih,
    const float* __restrict__ Whh, const float* __restrict__ bih,
    const float* __restrict__ bhh,
    unsigned long long* __restrict__ hx0, unsigned long long* __restrict__ hx1,
    unsigned long long* __restrict__ hx2, unsigned long long* __restrict__ hx3,
    float* __restrict__ h4g)
{
    __shared__ float es [NN * DD];     // 31 emb rows (tree-local)
    __shared__ float ps [8 * DD];      // GEMM partials (4 quarters x 64)
    __shared__ float xsl[NN * 64];     // x-gate slices incl. bias
    __shared__ float hs [8 * DD];      // staged input h rows
    __shared__ float cbuf[2 * 128];    // c ping-pong (block's 16 cols)
    __shared__ float bsl[64];
    __shared__ unsigned stag;

    const int tid  = threadIdx.x;
    const int t    = blockIdx.x >> 4;
    const int dt   = blockIdx.x & 15;
    const int kq   = tid >> 6;         // reduction quarter
    const int w    = tid & 63;         // owned gate-row within tile
    const int gate = w >> 4;
    const int col  = w & 15;
    const int grow = gate * DD + dt * 16 + col;

    if (tid == 0) {
        unsigned G = __hip_atomic_load(&g_gen[t * 16 + dt],
            __ATOMIC_RELAXED, __HIP_MEMORY_SCOPE_AGENT);
        __hip_atomic_store(&g_gen[t * 16 + dt], G + 1u,
            __ATOMIC_RELAXED, __HIP_MEMORY_SCOPE_AGENT);
        stag = G + 1u;
    }
    if (tid < 64) {
        int g2 = tid >> 4, c3 = tid & 15;
        int r2 = g2 * DD + dt * 16 + c3;
        bsl[tid] = bih[r2] + bhh[r2];
    }

    // ---- W_ih + W_hh quarter-rows -> registers (stationary)
    const float4* Wi4 = (const float4*)Wih + (size_t)grow * 64 + kq * 16;
    const float4* Wh4 = (const float4*)Whh + (size_t)grow * 64 + kq * 16;
    float4 wih[16], whh[16];
    #pragma unroll
    for (int j = 0; j < 16; ++j) { wih[j] = Wi4[j]; whh[j] = Wh4[j]; }

    // ---- emb tree rows -> LDS
    const float4* emb4 = (const float4*)emb + (size_t)t * NN * 64;
    float4* es4 = (float4*)es;
    #pragma unroll
    for (int r = 0; r < 8; ++r) {
        int idx = tid + 256 * r;                 // 0..2047, need < 1984
        if (idx < NN * 64) es4[idx] = emb4[idx];
    }
    __syncthreads();
    const unsigned tag = stag;

    // xproj batch [n0, n0+nn), nn <= 8: same fmaf chain / fold order as R9.
    auto xbatch = [&](int n0, int nn) {
        __syncthreads();               // prior epilogue may still read ps
        float acc[8];
        #pragma unroll
        for (int m = 0; m < 8; ++m) acc[m] = 0.f;
        #pragma unroll
        for (int j = 0; j < 16; ++j) {
            float4 wv = wih[j];
            #pragma unroll
            for (int m = 0; m < 8; ++m) {
                if (m < nn) {
                    float4 h = es4[(n0 + m) * 64 + kq * 16 + j];
                    acc[m] = fmaf(wv.x, h.x, fmaf(wv.y, h.y,
                             fmaf(wv.z, h.z, fmaf(wv.w, h.w, acc[m]))));
                }
            }
        }
        #pragma unroll
        for (int m = 0; m < 8; ++m)
            if (m < nn) ps[m * DD + kq * 64 + w] = acc[m];
        __syncthreads();
        #pragma unroll
        for (int rep = 0; rep < 2; ++rep) {
            int idx = tid + 256 * rep;           // 0..511
            if (idx < nn * 64) {
                int m = idx >> 6, w2 = idx & 63;
                xsl[(n0 + m) * 64 + w2] =
                      ps[m * DD +   0 + w2] + ps[m * DD +  64 + w2]
                    + ps[m * DD + 128 + w2] + ps[m * DD + 192 + w2] + bsl[w2];
            }
        }
        __syncthreads();
    };

    // ---- node 0 only, then root: publish h0 ASAP
    xbatch(0, 1);
    if (tid < 16) {
        float xi  = xsl[ 0 + tid];
        float xgg = xsl[32 + tid];
        float xo  = xsl[48 + tid];
        float c0 = sigf(xi) * tanh_f(xgg);        // h(-1)=c(-1)=0
        float h0 = sigf(xo) * tanh_f(c0);
        cbuf[tid] = c0;
        pub64(hx0 + (size_t)t * DD + dt * 16 + tid, tag, h0);
    }

    // ---- deferred work while h0 propagates
    xbatch(1, 6);                      // nodes 1..6 (steps 1-2 children)

    // ---- stage full h0
    {
        const unsigned long long* src = hx0 + (size_t)t * DD;
        unsigned long long v = ld64(src + tid);
        while ((unsigned)(v >> 32) != tag) {
            __builtin_amdgcn_s_sleep(1);
            v = ld64(src + tid);
        }
        union { unsigned u; float f; } cv; cv.u = (unsigned)v;
        hs[tid] = cv.f;
    }
    __syncthreads();

    const unsigned long long* hin[3] = { hx1, hx2, hx3 };
    unsigned long long* hout[3] = { hx1, hx2, hx3 };

    #pragma unroll
    for (int s = 1; s <= 4; ++s) {
        const int L = 1 << (s - 1);              // input rows per tree

        if (s > 1) {
            // poll-stage L full rows; per-word self-validating
            const unsigned long long* src = hin[s - 2] + (size_t)t * L * DD;
            unsigned long long v[8];
            #pragma unroll
            for (int r = 0; r < L; ++r) v[r] = ld64(src + tid + 256 * r);
            #pragma unroll
            for (int r = 0; r < L; ++r) {
                while ((unsigned)(v[r] >> 32) != tag) {
                    __builtin_amdgcn_s_sleep(1);
                    v[r] = ld64(src + tid + 256 * r);
                }
                union { unsigned u; float f; } cv; cv.u = (unsigned)v[r];
                hs[tid + 256 * r] = cv.f;
            }
            __syncthreads();
        }

        // GEMM: acc[p] = <W_hh[grow] quarter kq, h[p] quarter kq>
        const float4* hs4 = (const float4*)hs;
        float acc[8];
        #pragma unroll
        for (int p = 0; p < 8; ++p) acc[p] = 0.f;
        #pragma unroll
        for (int j = 0; j < 16; ++j) {
            float4 wv = whh[j];
            #pragma unroll
            for (int p = 0; p < L; ++p) {
                float4 h = hs4[p * 64 + kq * 16 + j];    // uniform broadcast
                acc[p] = fmaf(wv.x, h.x, fmaf(wv.y, h.y,
                         fmaf(wv.z, h.z, fmaf(wv.w, h.w, acc[p]))));
            }
        }
        #pragma unroll
        for (int p = 0; p < L; ++p) ps[p * DD + kq * 64 + w] = acc[p];
        __syncthreads();

        // Epilogue: parent p spawns children q=2p,2p+1; publish IMMEDIATELY
        if (tid < 32 * L) {
            const int p  = tid >> 5;
            const int c2 = tid & 15;
            const int q  = tid >> 4;             // child prefix, 0..2L-1
            float g0 = 0.f, g1 = 0.f, g2 = 0.f, g3 = 0.f;
            #pragma unroll
            for (int k = 0; k < 4; ++k) {
                const float* pp = ps + p * DD + k * 64;
                g0 += pp[ 0 + c2]; g1 += pp[16 + c2];
                g2 += pp[32 + c2]; g3 += pp[48 + c2];
            }
            const int node = (1 << s) - 1 + q;
            const float* xp = xsl + node * 64;
            float gi = g0 + xp[ 0 + c2];
            float gf = g1 + xp[16 + c2];
            float gg = g2 + xp[32 + c2];
            float go = g3 + xp[48 + c2];
            float cin = cbuf[((s - 1) & 1) * 128 + p * 16 + c2];
            float cn  = sigf(gf) * cin + sigf(gi) * tanh_f(gg);
            float hn  = sigf(go) * tanh_f(cn);
            if (s < 4) {
                cbuf[(s & 1) * 128 + q * 16 + c2] = cn;
                pub64(hout[s - 1] + (size_t)(t * 2 * L + q) * DD
                                  + dt * 16 + c2, tag, hn);
            } else {
                // launch boundary publishes h4 to the scatter kernel
                h4g[(size_t)(t * NL + q) * DD + dt * 16 + c2] = hn;
            }
        }

        // ---- deferred xproj while this step's h propagates to peers
        if (s == 1)      xbatch( 7, 8);          // nodes  7..14 (step 3)
        else if (s == 2) xbatch(15, 8);          // nodes 15..22 (step 4)
        else if (s == 3) xbatch(23, 8);          // nodes 23..30 (step 4)
    }
}

// ---------------------------------------------------------------------------
// K2: scatter out[b,t,:] = h4[t*16 + argmax(cross[b,t,:]), :]
// One wave per (b,t) row (40960 waves): ballot -> leaf, float4 row copy.
// (Proven R2 version.)
// ---------------------------------------------------------------------------
__global__ __launch_bounds__(256) void k_scatter(
    const float* __restrict__ cross, const float* __restrict__ htab,
    float* __restrict__ out)
{
    const int tid  = threadIdx.x;
    const int wave = tid >> 6;
    const int lane = tid & 63;
    const int r = blockIdx.x * 4 + wave;     // 0..40959 = b*10 + t
    const int b = r / NT;
    const int t = r - b * NT;

    float v = 0.f;
    if (lane < NL) v = cross[(size_t)b * (NT * NL) + t * NL + lane];
    unsigned long long m = __ballot(v > 0.5f);
    int leaf = m ? (int)__builtin_ctzll(m) : 0;
    int p = t * NL + leaf;

    const float4* h4 = (const float4*)htab;
    float4* o4 = (float4*)out;
    o4[(size_t)r * 64 + lane] = h4[(size_t)p * 64 + lane];
}

// ---------------------------------------------------------------------------
extern "C" void kernel_launch(void* const* d_in, const int* in_sizes, int n_in,
                              void* d_out, int out_size, void* d_ws, size_t ws_size,
                              hipStream_t stream)
{
    const float* cross = (const float*)d_in[0];
    const float* emb   = (const float*)d_in[1];
    const float* Wih   = (const float*)d_in[2];
    const float* Whh   = (const float*)d_in[3];
    const float* bih   = (const float*)d_in[4];
    const float* bhh   = (const float*)d_in[5];
    float* out = (float*)d_out;

    unsigned long long* hx0 = (unsigned long long*)d_ws;   // 10*256 u64
    unsigned long long* hx1 = hx0 + (size_t)NT * DD;       // 20*256
    unsigned long long* hx2 = hx1 + (size_t)2 * NT * DD;   // 40*256
    unsigned long long* hx3 = hx2 + (size_t)4 * NT * DD;   // 80*256
    float* h4g = (float*)(hx3 + (size_t)8 * NT * DD);      // 160*256 f32

    hipLaunchKernelGGL(k_treelstm, dim3(160), dim3(256), 0, stream,
                       emb, Wih, Whh, bih, bhh, hx0, hx1, hx2, hx3, h4g);
    hipLaunchKernelGGL(k_scatter, dim3(10240), dim3(256), 0, stream,
                       cross, h4g, out);
}